// Round 6
// baseline (126.952 us; speedup 1.0000x reference)
//
#include <hip/hip_runtime.h>
#include <math.h>

// LinearAttention1d: b=8, dim=64, t=16384, heads=4, dim_head=32, inner=128
//
// Collapsed math (exp-safe without max subtraction: q_raw,k_raw ~ N(0,1)):
//   Zq[b,c]   = sum_t exp(q_raw[c,t])
//   ksum[b,c] = sum_t exp(k_raw[c,t]) / Zt[b,h,t]   (softmax over d=32 per t)
//   vsum[b,c] = Wv[c,:] . xsum[b,:]
//   y[b,o,t]  = sum_c wout[o,c]*ksum*vsum/Zq * exp(q_raw[c,t]) + b_out[o]
//
// R17 = BARRIER-FREE k2. R16 (fewer WGs) regressed -> per-block serial time
// is real; ramp theory dead. Model: dur = 42 us ws-poison fill (harness) +
// k1 (~35) + k2 (~35). k2's time is barrier-bound: one 8 KB LDS tile in
// flight, __syncthreads round-trip per tile = HBM latency on the critical
// path 16x. But P was materialized by k1 in EXACTLY the B-frag layout
// ([t][c], c contiguous), so lanes can load B-frags STRAIGHT from global:
//   bp[s] = *(short8*)&Pb[(t+lm)*NI + s*32 + quad*8]
// (full 128-B line utilization across quads+s). k2 now has NO LDS tile and
// NO barriers in the main loop -> compiler pipelines loads across all 16
// tiles, MLP no longer capped at one tile. k1 byte-identical to R15.
// Predict k2 ~12-15 us, total ~95-105. Neutral => declare harness floor.
// MFMA 16x16x32 bf16 layouts (verified): A[m=lane&15][k=quad*8+j],
//   B[k=quad*8+j][n=lane&15], C col=lane&15, row=quad*4+reg.

typedef short short8 __attribute__((ext_vector_type(8)));
typedef short short4s __attribute__((ext_vector_type(4)));
typedef float f32x4 __attribute__((ext_vector_type(4)));

namespace {
constexpr int NB = 8;
constexpr int NC = 64;           // in/out channels
constexpr int NT = 16384;
constexpr int NI = 128;          // inner = heads*dim_head
constexpr int TBK = 256;         // timesteps per block
constexpr int CPB = NT / TBK;    // 64 chunks per batch
constexpr int NBLK = NB * CPB;   // 512 blocks
constexpr int XSP = 72;          // xs[t][c] bf16 row stride

// ws: deterministic per-chunk partial slots + P buffer. No memset, no atomics.
constexpr int F_ZQ = 0;                  // [NI]
constexpr int F_KS = NI;                 // [NI]
constexpr int F_XS = 2 * NI;             // [NC]
constexpr int SLOT = 2 * NI + NC;        // 320 floats
constexpr int WS_NFLOAT = NB * CPB * SLOT;        // 163,840 floats = 640 KB
constexpr size_t P_ELEMS = (size_t)NB * NT * NI;  // bf16 elems = 33.55 M
constexpr size_t WS_BYTES_NEEDED = (size_t)WS_NFLOAT * 4 + P_ELEMS * 2;  // ~34.2 MB
}

__device__ __forceinline__ unsigned short f2bf(float f) {
  unsigned u = __float_as_uint(f);
  u += 0x7fffu + ((u >> 16) & 1u);   // RNE
  return (unsigned short)(u >> 16);
}

// stage x strip (fp32, coalesced float4) -> bf16 xs[t][c]; xsum plain store
__device__ __forceinline__ void stage_x(const float* __restrict__ xb, int t0,
                                        unsigned short* xs, float* xsum_dst, int tid) {
  const int c = tid >> 2, tq = tid & 3;
  const float4* xr = (const float4*)(xb + (size_t)c * NT + t0);
  float s = 0.f;
#pragma unroll 4
  for (int i = 0; i < TBK / 16; ++i) {
    const int tv = tq + 4 * i;
    float4 v = xr[tv];
    s += (v.x + v.y) + (v.z + v.w);
    const int t = 4 * tv;
    xs[(t + 0) * XSP + c] = f2bf(v.x);
    xs[(t + 1) * XSP + c] = f2bf(v.y);
    xs[(t + 2) * XSP + c] = f2bf(v.z);
    xs[(t + 3) * XSP + c] = f2bf(v.w);
  }
  s += __shfl_xor(s, 1, 64);
  s += __shfl_xor(s, 2, 64);
  if (tq == 0) xsum_dst[c] = s;          // plain store into this block's slot
}

// load Wq A-frags for rows 32w..32w+31 (2 row-tiles x 2 K-steps)
__device__ __forceinline__ void load_aq(const float* __restrict__ wqkv, int w,
                                        int lm, int quad, short8 aq[2][2]) {
#pragma unroll
  for (int tile = 0; tile < 2; ++tile)
#pragma unroll
    for (int s = 0; s < 2; ++s) {
      const float* pq = wqkv + (size_t)(32 * w + tile * 16 + lm) * NC + s * 32 + quad * 8;
#pragma unroll
      for (int j = 0; j < 8; ++j) aq[tile][s][j] = (short)f2bf(pq[j]);
    }
}

// ---------------------------------------------------------------------------
// k1: stats + P materialization. 512 blocks, wave = head. (byte-identical R15)
// ---------------------------------------------------------------------------
__global__ __launch_bounds__(256) void la_stats(
    const float* __restrict__ x, const float* __restrict__ wqkv,
    float* __restrict__ ws)
{
  __shared__ __align__(16) unsigned short xs[TBK * XSP];  // 36,864 B

  const int bid = blockIdx.x;
  const int b = bid >> 6, chunk = bid & 63;
  const int tid = threadIdx.x, lane = tid & 63;
  const int w = __builtin_amdgcn_readfirstlane(tid >> 6);
  const int lm = lane & 15, quad = lane >> 4;
  const float* xb = x + (size_t)b * NC * NT;
  float* slot = ws + (size_t)(b * CPB + chunk) * SLOT;
  // P[t][c] bf16, per-chunk base (t-major, c contiguous)
  unsigned short* Pb = (unsigned short*)(ws + WS_NFLOAT)
                       + (size_t)(b * CPB + chunk) * TBK * NI;

  stage_x(xb, chunk * TBK, xs, slot + F_XS, tid);

  short8 aq[2][2], ak[2][2];
  load_aq(wqkv, w, lm, quad, aq);
#pragma unroll
  for (int tile = 0; tile < 2; ++tile)
#pragma unroll
    for (int s = 0; s < 2; ++s) {
      const float* pk = wqkv + (size_t)(NI + 32 * w + tile * 16 + lm) * NC + s * 32 + quad * 8;
#pragma unroll
      for (int j = 0; j < 8; ++j) ak[tile][s][j] = (short)f2bf(pk[j]);
    }

  float zq_acc[2][4] = {};
  float ks_acc[2][4] = {};
  __syncthreads();

  for (int tc = 0; tc < TBK / 16; ++tc) {
    short8 bf[2];
#pragma unroll
    for (int s = 0; s < 2; ++s)
      bf[s] = *(const short8*)&xs[(tc * 16 + lm) * XSP + s * 32 + quad * 8];
    f32x4 cq[2] = {{0,0,0,0},{0,0,0,0}}, ck[2] = {{0,0,0,0},{0,0,0,0}};
#pragma unroll
    for (int tile = 0; tile < 2; ++tile)
#pragma unroll
      for (int s = 0; s < 2; ++s) {
        cq[tile] = __builtin_amdgcn_mfma_f32_16x16x32_bf16(aq[tile][s], bf[s], cq[tile], 0, 0, 0);
        ck[tile] = __builtin_amdgcn_mfma_f32_16x16x32_bf16(ak[tile][s], bf[s], ck[tile], 0, 0, 0);
      }
    float ke[2][4];
    float zt = 0.f;
#pragma unroll
    for (int tile = 0; tile < 2; ++tile) {
      short4s pv;
#pragma unroll
      for (int r = 0; r < 4; ++r) {
        float eq = __expf(cq[tile][r]);
        zq_acc[tile][r] += eq;
        pv[r] = (short)f2bf(eq);           // P = exp(q) in bf16
        float e = __expf(ck[tile][r]);
        ke[tile][r] = e;
        zt += e;
      }
      // C layout: col(t-within-16)=lm, row(c-within-16)=quad*4+r.
      *(short4s*)&Pb[(size_t)(tc * 16 + lm) * NI + 32 * w + tile * 16 + quad * 4] = pv;
    }
    zt += __shfl_xor(zt, 16, 64);   // k rows live across quads; col fixed
    zt += __shfl_xor(zt, 32, 64);
    const float rz = __builtin_amdgcn_rcpf(zt);
#pragma unroll
    for (int tile = 0; tile < 2; ++tile)
#pragma unroll
      for (int r = 0; r < 4; ++r)
        ks_acc[tile][r] = fmaf(ke[tile][r], rz, ks_acc[tile][r]);
  }

  // reduce over 16 cols, one plain store per channel into this block's slot
#pragma unroll
  for (int tile = 0; tile < 2; ++tile)
#pragma unroll
    for (int r = 0; r < 4; ++r) {
      float a = zq_acc[tile][r], k = ks_acc[tile][r];
#pragma unroll
      for (int off = 1; off < 16; off <<= 1) {
        a += __shfl_xor(a, off, 64);
        k += __shfl_xor(k, off, 64);
      }
      if (lm == 0) {
        const int c = 32 * w + tile * 16 + quad * 4 + r;
        slot[F_ZQ + c] = a;
        slot[F_KS + c] = k;
      }
    }
}

// ---------------------------------------------------------------------------
// k2: BARRIER-FREE streaming GEMM. Prologue sums chunk slots -> Weff; main
// loop reads B-frags straight from global P (no LDS tile, no syncthreads).
// ---------------------------------------------------------------------------
__global__ __launch_bounds__(256) void la_gemm(
    const float* __restrict__ wqkv, const float* __restrict__ wout,
    const float* __restrict__ bout, const float* __restrict__ ws,
    float* __restrict__ y)
{
  __shared__ float scale_s[NI];
  __shared__ float xsum_s[NC];

  const int bid = blockIdx.x;
  const int b = bid >> 6, chunk = bid & 63;
  const int tid = threadIdx.x, lane = tid & 63;
  const int w = __builtin_amdgcn_readfirstlane(tid >> 6);
  const int lm = lane & 15, quad = lane >> 4;
  const int t0 = chunk * TBK;
  const float* wsb = ws + (size_t)b * CPB * SLOT;
  const unsigned short* Pb = (const unsigned short*)(ws + WS_NFLOAT)
                             + (size_t)(b * CPB + chunk) * TBK * NI;

  // ---- prologue: sum 64 chunk slots (L2-resident) -> scale_s ----
  if (tid < NC) {
    float s = 0.f;
#pragma unroll 8
    for (int sl = 0; sl < CPB; ++sl) s += wsb[(size_t)sl * SLOT + F_XS + tid];
    xsum_s[tid] = s;
  }
  __syncthreads();
  if (tid < NI) {
    float vs = 0.f;
    const float* wv = wqkv + (size_t)(2 * NI + tid) * NC;
#pragma unroll 8
    for (int cc = 0; cc < NC; ++cc) vs = fmaf(wv[cc], xsum_s[cc], vs);
    float zq_t = 0.f, ks_t = 0.f;
#pragma unroll 8
    for (int sl = 0; sl < CPB; ++sl) {
      zq_t += wsb[(size_t)sl * SLOT + F_ZQ + tid];
      ks_t += wsb[(size_t)sl * SLOT + F_KS + tid];
    }
    scale_s[tid] = ks_t * vs / zq_t;
  }
  __syncthreads();

  // ---- A-frags: Weff rows 16w.. (K=128) ; bias ----
  short8 aw[4];
  {
    const int o = 16 * w + lm;
#pragma unroll
    for (int s = 0; s < 4; ++s) {
      const float* wo = wout + (size_t)o * NI + s * 32 + quad * 8;
#pragma unroll
      for (int j = 0; j < 8; ++j)
        aw[s][j] = (short)f2bf(wo[j] * scale_s[s * 32 + quad * 8 + j]);
    }
  }
  float bias[4];
#pragma unroll
  for (int r = 0; r < 4; ++r) bias[r] = bout[16 * w + quad * 4 + r];

  // ---- main loop: 16 independent 16-t tiles, zero barriers ----
  // B-frag straight from global: row t0+tile*16+lm (256 B), cols s*32+quad*8.
  // 4 quads x 4 s-steps cover each 256-B row fully -> full line utilization.
  const unsigned short* Prow = Pb + (size_t)lm * NI + quad * 8;
  float* yrow = y + ((size_t)b * NC + 16 * w + quad * 4) * NT + t0 + lm;
#pragma unroll 4
  for (int tile = 0; tile < TBK / 16; ++tile) {
    const unsigned short* Pr = Prow + (size_t)tile * 16 * NI;
    short8 bp[4];
#pragma unroll
    for (int s = 0; s < 4; ++s)
      bp[s] = *(const short8*)&Pr[s * 32];
    f32x4 acc = {bias[0], bias[1], bias[2], bias[3]};
#pragma unroll
    for (int s = 0; s < 4; ++s)
      acc = __builtin_amdgcn_mfma_f32_16x16x32_bf16(aw[s], bp[s], acc, 0, 0, 0);
#pragma unroll
    for (int r = 0; r < 4; ++r)
      yrow[(size_t)r * NT + tile * 16] = acc[r];
  }
}

// ---------------------------------------------------------------------------
extern "C" void kernel_launch(void* const* d_in, const int* in_sizes, int n_in,
                              void* d_out, int out_size, void* d_ws, size_t ws_size,
                              hipStream_t stream)
{
  const float* x    = (const float*)d_in[0];
  const float* wqkv = (const float*)d_in[1];
  const float* wout = (const float*)d_in[2];
  const float* bout = (const float*)d_in[3];
  float* y  = (float*)d_out;
  float* ws = (float*)d_ws;

  // Guard: convert any workspace shortfall into a clean absmax failure.
  if (ws_size < WS_BYTES_NEEDED) return;

  la_stats<<<dim3(NBLK), 256, 0, stream>>>(x, wqkv, ws);
  la_gemm<<<dim3(NBLK), 256, 0, stream>>>(wqkv, wout, bout, ws, y);
}

// Round 7
// 116.235 us; speedup vs baseline: 1.0922x; 1.0922x over previous
//
#include <hip/hip_runtime.h>
#include <math.h>

// LinearAttention1d: b=8, dim=64, t=16384, heads=4, dim_head=32, inner=128
//
// Collapsed math (exp-safe without max subtraction: q_raw,k_raw ~ N(0,1)):
//   Zq[b,c]   = sum_t exp(q_raw[c,t])
//   ksum[b,c] = sum_t exp(k_raw[c,t]) / Zt[b,h,t]   (softmax over d=32 per t)
//   vsum[b,c] = Wv[c,:] . xsum[b,:]
//   y[b,o,t]  = sum_c wout[o,c]*ksum*vsum/Zq * exp(q_raw[c,t]) + b_out[o]
//
// R18 = MAX MLP IN k1. R17's barrier-free k2 REGRESSED (127 vs 117.6) ->
// staged k2 restored (R15 form). Surviving anomaly: k1 fetches exactly x
// (34.7 MB, zero over-fetch) in 44 us = 0.76 TB/s with all pipes idle ->
// memory-LATENCY bound, too few loads in flight. stage_x's load->convert->
// ds_write body (unroll 4) caps in-flight at ~4x16B/lane behind a vmcnt
// ladder. Fix: two-phase staging — 16 independent float4 loads into regs
// (unroll 16, ~64 VGPR, LDS already caps us at 4 blocks/CU so no occupancy
// loss), THEN convert+write. Weight-frag loads hoisted before staging to
// overlap the same latency. Everything else byte-identical to R15.
// Predict k1 44->~30, total ~100-105. Neutral => latency theory dead,
// declare floor (fill 42 us is at BW roofline; kernels at dispatch floor).
// MFMA 16x16x32 bf16 layouts (verified): A[m=lane&15][k=quad*8+j],
//   B[k=quad*8+j][n=lane&15], C col=lane&15, row=quad*4+reg.

typedef short short8 __attribute__((ext_vector_type(8)));
typedef short short4s __attribute__((ext_vector_type(4)));
typedef float f32x4 __attribute__((ext_vector_type(4)));

namespace {
constexpr int NB = 8;
constexpr int NC = 64;           // in/out channels
constexpr int NT = 16384;
constexpr int NI = 128;          // inner = heads*dim_head
constexpr int TBK = 256;         // timesteps per block
constexpr int CPB = NT / TBK;    // 64 chunks per batch
constexpr int NBLK = NB * CPB;   // 512 blocks
constexpr int XSP = 72;          // xs[t][c] bf16 row stride
constexpr int PTP = 136;         // p-tile [t][c] bf16 row stride (padded)
constexpr int PT  = 32;          // p subtile timesteps per stage

// ws: deterministic per-chunk partial slots + P buffer. No memset, no atomics.
constexpr int F_ZQ = 0;                  // [NI]
constexpr int F_KS = NI;                 // [NI]
constexpr int F_XS = 2 * NI;             // [NC]
constexpr int SLOT = 2 * NI + NC;        // 320 floats
constexpr int WS_NFLOAT = NB * CPB * SLOT;        // 163,840 floats = 640 KB
constexpr size_t P_ELEMS = (size_t)NB * NT * NI;  // bf16 elems = 33.55 M
constexpr size_t WS_BYTES_NEEDED = (size_t)WS_NFLOAT * 4 + P_ELEMS * 2;  // ~34.2 MB
}

__device__ __forceinline__ unsigned short f2bf(float f) {
  unsigned u = __float_as_uint(f);
  u += 0x7fffu + ((u >> 16) & 1u);   // RNE
  return (unsigned short)(u >> 16);
}

// stage x strip: PHASE 1 = 16 independent float4 loads into registers
// (max loads in flight), PHASE 2 = convert + LDS write. xsum plain store.
__device__ __forceinline__ void stage_x(const float* __restrict__ xb, int t0,
                                        unsigned short* xs, float* xsum_dst, int tid) {
  const int c = tid >> 2, tq = tid & 3;
  const float4* xr = (const float4*)(xb + (size_t)c * NT + t0);
  float4 v[16];
#pragma unroll
  for (int i = 0; i < 16; ++i) v[i] = xr[tq + 4 * i];   // all 16 in flight
  float s = 0.f;
#pragma unroll
  for (int i = 0; i < 16; ++i) {
    s += (v[i].x + v[i].y) + (v[i].z + v[i].w);
    const int t = 4 * (tq + 4 * i);
    xs[(t + 0) * XSP + c] = f2bf(v[i].x);
    xs[(t + 1) * XSP + c] = f2bf(v[i].y);
    xs[(t + 2) * XSP + c] = f2bf(v[i].z);
    xs[(t + 3) * XSP + c] = f2bf(v[i].w);
  }
  s += __shfl_xor(s, 1, 64);
  s += __shfl_xor(s, 2, 64);
  if (tq == 0) xsum_dst[c] = s;          // plain store into this block's slot
}

// load Wq A-frags for rows 32w..32w+31 (2 row-tiles x 2 K-steps)
__device__ __forceinline__ void load_aq(const float* __restrict__ wqkv, int w,
                                        int lm, int quad, short8 aq[2][2]) {
#pragma unroll
  for (int tile = 0; tile < 2; ++tile)
#pragma unroll
    for (int s = 0; s < 2; ++s) {
      const float* pq = wqkv + (size_t)(32 * w + tile * 16 + lm) * NC + s * 32 + quad * 8;
#pragma unroll
      for (int j = 0; j < 8; ++j) aq[tile][s][j] = (short)f2bf(pq[j]);
    }
}

// ---------------------------------------------------------------------------
// k1: stats + P materialization. 512 blocks, wave = head.
// ---------------------------------------------------------------------------
__global__ __launch_bounds__(256) void la_stats(
    const float* __restrict__ x, const float* __restrict__ wqkv,
    float* __restrict__ ws)
{
  __shared__ __align__(16) unsigned short xs[TBK * XSP];  // 36,864 B

  const int bid = blockIdx.x;
  const int b = bid >> 6, chunk = bid & 63;
  const int tid = threadIdx.x, lane = tid & 63;
  const int w = __builtin_amdgcn_readfirstlane(tid >> 6);
  const int lm = lane & 15, quad = lane >> 4;
  const float* xb = x + (size_t)b * NC * NT;
  float* slot = ws + (size_t)(b * CPB + chunk) * SLOT;
  // P[t][c] bf16, per-chunk base (t-major, c contiguous)
  unsigned short* Pb = (unsigned short*)(ws + WS_NFLOAT)
                       + (size_t)(b * CPB + chunk) * TBK * NI;

  // weight frags FIRST: their latency overlaps the x staging loads
  short8 aq[2][2], ak[2][2];
  load_aq(wqkv, w, lm, quad, aq);
#pragma unroll
  for (int tile = 0; tile < 2; ++tile)
#pragma unroll
    for (int s = 0; s < 2; ++s) {
      const float* pk = wqkv + (size_t)(NI + 32 * w + tile * 16 + lm) * NC + s * 32 + quad * 8;
#pragma unroll
      for (int j = 0; j < 8; ++j) ak[tile][s][j] = (short)f2bf(pk[j]);
    }

  stage_x(xb, chunk * TBK, xs, slot + F_XS, tid);

  float zq_acc[2][4] = {};
  float ks_acc[2][4] = {};
  __syncthreads();

  for (int tc = 0; tc < TBK / 16; ++tc) {
    short8 bf[2];
#pragma unroll
    for (int s = 0; s < 2; ++s)
      bf[s] = *(const short8*)&xs[(tc * 16 + lm) * XSP + s * 32 + quad * 8];
    f32x4 cq[2] = {{0,0,0,0},{0,0,0,0}}, ck[2] = {{0,0,0,0},{0,0,0,0}};
#pragma unroll
    for (int tile = 0; tile < 2; ++tile)
#pragma unroll
      for (int s = 0; s < 2; ++s) {
        cq[tile] = __builtin_amdgcn_mfma_f32_16x16x32_bf16(aq[tile][s], bf[s], cq[tile], 0, 0, 0);
        ck[tile] = __builtin_amdgcn_mfma_f32_16x16x32_bf16(ak[tile][s], bf[s], ck[tile], 0, 0, 0);
      }
    float ke[2][4];
    float zt = 0.f;
#pragma unroll
    for (int tile = 0; tile < 2; ++tile) {
      short4s pv;
#pragma unroll
      for (int r = 0; r < 4; ++r) {
        float eq = __expf(cq[tile][r]);
        zq_acc[tile][r] += eq;
        pv[r] = (short)f2bf(eq);           // P = exp(q) in bf16
        float e = __expf(ck[tile][r]);
        ke[tile][r] = e;
        zt += e;
      }
      // C layout: col(t-within-16)=lm, row(c-within-16)=quad*4+r.
      *(short4s*)&Pb[(size_t)(tc * 16 + lm) * NI + 32 * w + tile * 16 + quad * 4] = pv;
    }
    zt += __shfl_xor(zt, 16, 64);   // k rows live across quads; col fixed
    zt += __shfl_xor(zt, 32, 64);
    const float rz = __builtin_amdgcn_rcpf(zt);
#pragma unroll
    for (int tile = 0; tile < 2; ++tile)
#pragma unroll
      for (int r = 0; r < 4; ++r)
        ks_acc[tile][r] = fmaf(ke[tile][r], rz, ks_acc[tile][r]);
  }

  // reduce over 16 cols, one plain store per channel into this block's slot
#pragma unroll
  for (int tile = 0; tile < 2; ++tile)
#pragma unroll
    for (int r = 0; r < 4; ++r) {
      float a = zq_acc[tile][r], k = ks_acc[tile][r];
#pragma unroll
      for (int off = 1; off < 16; off <<= 1) {
        a += __shfl_xor(a, off, 64);
        k += __shfl_xor(k, off, 64);
      }
      if (lm == 0) {
        const int c = 32 * w + tile * 16 + quad * 4 + r;
        slot[F_ZQ + c] = a;
        slot[F_KS + c] = k;
      }
    }
}

// ---------------------------------------------------------------------------
// k2: pure GEMM (R15 staged form). Prologue sums chunk slots -> Weff;
// stage 32-t P tile (coalesced short8) -> 4 MFMA -> y.
// ---------------------------------------------------------------------------
__global__ __launch_bounds__(256) void la_gemm(
    const float* __restrict__ wqkv, const float* __restrict__ wout,
    const float* __restrict__ bout, const float* __restrict__ ws,
    float* __restrict__ y)
{
  __shared__ __align__(16) unsigned short ptile[PT * PTP];  // 8,704 B
  __shared__ float scale_s[NI];
  __shared__ float xsum_s[NC];

  const int bid = blockIdx.x;
  const int b = bid >> 6, chunk = bid & 63;
  const int tid = threadIdx.x, lane = tid & 63;
  const int w = __builtin_amdgcn_readfirstlane(tid >> 6);
  const int lm = lane & 15, quad = lane >> 4;
  const int t0 = chunk * TBK;
  const float* wsb = ws + (size_t)b * CPB * SLOT;
  const unsigned short* Pb = (const unsigned short*)(ws + WS_NFLOAT)
                             + (size_t)(b * CPB + chunk) * TBK * NI;

  // ---- prologue: sum 64 chunk slots (L2-resident) -> scale_s ----
  if (tid < NC) {
    float s = 0.f;
#pragma unroll 8
    for (int sl = 0; sl < CPB; ++sl) s += wsb[(size_t)sl * SLOT + F_XS + tid];
    xsum_s[tid] = s;
  }
  __syncthreads();
  if (tid < NI) {
    float vs = 0.f;
    const float* wv = wqkv + (size_t)(2 * NI + tid) * NC;
#pragma unroll 8
    for (int cc = 0; cc < NC; ++cc) vs = fmaf(wv[cc], xsum_s[cc], vs);
    float zq_t = 0.f, ks_t = 0.f;
#pragma unroll 8
    for (int sl = 0; sl < CPB; ++sl) {
      zq_t += wsb[(size_t)sl * SLOT + F_ZQ + tid];
      ks_t += wsb[(size_t)sl * SLOT + F_KS + tid];
    }
    scale_s[tid] = ks_t * vs / zq_t;
  }
  __syncthreads();

  // ---- A-frags: Weff rows 16w.. (K=128) ; bias ----
  short8 aw[4];
  {
    const int o = 16 * w + lm;
#pragma unroll
    for (int s = 0; s < 4; ++s) {
      const float* wo = wout + (size_t)o * NI + s * 32 + quad * 8;
#pragma unroll
      for (int j = 0; j < 8; ++j)
        aw[s][j] = (short)f2bf(wo[j] * scale_s[s * 32 + quad * 8 + j]);
    }
  }
  float bias[4];
#pragma unroll
  for (int r = 0; r < 4; ++r) bias[r] = bout[16 * w + quad * 4 + r];

  // ---- main loop: stage 32-t P tile (coalesced) -> y GEMM ----
  const int tl0 = tid >> 4;            // 0..15: row within half-tile
  const int coff = (tid & 15) * 8;     // 0..120: channel offset (short8)
  for (int sub = 0; sub < TBK / PT; ++sub) {
#pragma unroll
    for (int i = 0; i < 2; ++i) {
      const int tl = i * 16 + tl0;
      short8 v = *(const short8*)&Pb[(size_t)(sub * PT + tl) * NI + coff];
      *(short8*)&ptile[tl * PTP + coff] = v;
    }
    __syncthreads();
    for (int tc = 0; tc < PT / 16; ++tc) {
      short8 bp[4];
#pragma unroll
      for (int s = 0; s < 4; ++s)
        bp[s] = *(const short8*)&ptile[(tc * 16 + lm) * PTP + s * 32 + quad * 8];
      f32x4 acc = {bias[0], bias[1], bias[2], bias[3]};
#pragma unroll
      for (int s = 0; s < 4; ++s)
        acc = __builtin_amdgcn_mfma_f32_16x16x32_bf16(aw[s], bp[s], acc, 0, 0, 0);
#pragma unroll
      for (int r = 0; r < 4; ++r)
        y[((size_t)b * NC + 16 * w + quad * 4 + r) * NT + t0 + sub * PT + tc * 16 + lm] = acc[r];
    }
    __syncthreads();
  }
}

// ---------------------------------------------------------------------------
extern "C" void kernel_launch(void* const* d_in, const int* in_sizes, int n_in,
                              void* d_out, int out_size, void* d_ws, size_t ws_size,
                              hipStream_t stream)
{
  const float* x    = (const float*)d_in[0];
  const float* wqkv = (const float*)d_in[1];
  const float* wout = (const float*)d_in[2];
  const float* bout = (const float*)d_in[3];
  float* y  = (float*)d_out;
  float* ws = (float*)d_ws;

  // Guard: convert any workspace shortfall into a clean absmax failure.
  if (ws_size < WS_BYTES_NEEDED) return;

  la_stats<<<dim3(NBLK), 256, 0, stream>>>(x, wqkv, ws);
  la_gemm<<<dim3(NBLK), 256, 0, stream>>>(wqkv, wout, bout, ws, y);
}